// Round 7
// baseline (353.152 us; speedup 1.0000x reference)
//
#include <hip/hip_runtime.h>
#include <hip/hip_bf16.h>

#define Nn 8192
#define Tt 32
#define Ff 16
#define Hh 128
#define HEADS 4
#define Ee 2048
#define NNZ 65536
#define TF (Tt*Ff)       // 512
#define BN_EPS 1e-5f

// All float tensors are float32 per the reference.

typedef __attribute__((ext_vector_type(8))) short bf8_t;   // 8 bf16 lanes (4 VGPRs)
typedef __attribute__((ext_vector_type(4))) float f4_t;
typedef __attribute__((ext_vector_type(4))) short s4_t;
#define MFMA16(a,b,c) __builtin_amdgcn_mfma_f32_16x16x32_bf16(a,b,c,0,0,0)

__device__ __forceinline__ short f2bf(float v){
  union { __hip_bfloat16 h; short s; } u;
  u.h = __float2bfloat16(v);
  return u.s;
}
__device__ __forceinline__ float bf2f(short s){
  union { __hip_bfloat16 h; short s2; } u;
  u.s2 = s;
  return __bfloat162float(u.h);
}
__device__ __forceinline__ float fsigmoid(float x){
  return __builtin_amdgcn_rcpf(1.f + __expf(-x));
}
__device__ __forceinline__ float ftanh(float x){
  return 1.f - 2.f*__builtin_amdgcn_rcpf(__expf(2.f*x) + 1.f);
}
__device__ __forceinline__ float lrelu02(float x){ return (x >= 0.f) ? x : 0.2f*x; }
// Barrier that waits only on LDS ops (global stores/prefetch stay in flight).
__device__ __forceinline__ void bar_lgkm(){
  asm volatile("s_waitcnt lgkmcnt(0)\n\ts_barrier" ::: "memory");
}

// ---------------- static scratch (fully rewritten every call) ----------------
__device__ __align__(16) short g_inxb[Nn*TF];   // bn1 output bf16, (T, N, F)
__device__ __align__(16) short g_hsb[Nn*Tt*Hh]; // GRU hidden states bf16, (N, T, H)
__device__ float  g_q[Nn*Hh];            // query = h31 @ Wq^T (gru epilogue)
__device__ __align__(16) short g_cmbb[Nn*2*Hh]; // [mixsum | q] per node, bf16
__device__ __align__(16) short g_nfb[Nn*Hh];     // nf bf16
__device__ __align__(16) short g_woutb[Hh*256];  // Wout as bf16
__device__ __align__(16) short g_w1b[4*Hh*Hh];   // W1 as bf16
__device__ __align__(16) short g_w2b[Hh*Hh];     // W2 as bf16
__device__ __align__(16) short g_xwb[Nn*4*Hh];   // bn2(nf)@W1^T bf16, layout (n, c*4+hd)
__device__ __align__(16) short g_x1b[Nn*Hh];     // layer-1 node out, bf16
__device__ __align__(16) short g_xw2b[Nn*Hh];    // x1 @ W2^T, bf16
__device__ __align__(16) short g_eoutb[Ee*4*Hh]; // edge agg 1 bf16, layout (d, c*4+hd)
__device__ __align__(16) short g_eout2b[Ee*Hh];  // edge agg 2, bf16
__device__ float  g_px1[Nn*HEADS];       // att dots
__device__ float  g_pe1[Ee*HEADS];
__device__ float  g_pa2[Nn];
__device__ float  g_pb2[Ee];
__device__ __align__(16) float g_al1[NNZ*HEADS]; // memoized softmax alphas, layer 1
__device__ float  g_al2[NNZ];                    // layer 2
__device__ float  g_w1x[HEADS*Hh];       // precomputed W^T-att folds
__device__ float  g_w1a[HEADS*Hh];
__device__ float  g_w2x[Hh];
__device__ float  g_w2a[Hh];
__device__ float  g_p1s[512*TF];         // bn1 partials
__device__ float  g_p1q[512*TF];
__device__ float  g_bn1s[TF], g_bn1b[TF];
__device__ float  g_bn2acc[256];         // [0:128) col sums of nf, [128:256) sumsq
__device__ int    g_D[Nn];
__device__ int    g_rowptr[Nn+1];
__device__ int    g_cursor[Nn];
__device__ int    g_eidx[NNZ];

// ---------------- K1: bn1 partials + zero accums (0..511) | w-folds (512,513) | bf16 weight converts (514..520) ----------------
__global__ __launch_bounds__(256) void k_pre(const float* __restrict__ x,
                                             const float* __restrict__ W1,
                                             const float* __restrict__ att1,
                                             const float* __restrict__ W2,
                                             const float* __restrict__ att2,
                                             const float* __restrict__ Wout){
  int b = blockIdx.x, tid = threadIdx.x;
  if(b >= 512){
    if(b == 512){
      // w1x[hd,k] = sum_c W1[(hd*128+c)*128+k]*att1[hd*256+c]; w1a likewise with +128
      for(int p = 0; p < 2; p++){
        int idx = p*256 + tid;           // 512 entries
        int hd = idx >> 7, k = idx & 127;
        float sx = 0.f, sa = 0.f;
        for(int c = 0; c < 128; c++){
          float wv = W1[(hd*128 + c)*128 + k];
          sx += wv*att1[hd*256 + c];
          sa += wv*att1[hd*256 + 128 + c];
        }
        g_w1x[idx] = sx; g_w1a[idx] = sa;
      }
    } else if(b == 513){
      int k = tid & 127;
      if(tid < 128){
        float s = 0.f;
        for(int c = 0; c < 128; c++) s += W2[c*128 + k]*att2[c];
        g_w2x[k] = s;
      } else {
        float s = 0.f;
        for(int c = 0; c < 128; c++) s += W2[c*128 + k]*att2[128 + c];
        g_w2a[k] = s;
      }
    } else if(b < 516){
      int i0 = (b - 514)*16384;
      for(int j = tid; j < 16384; j += 256) g_woutb[i0 + j] = f2bf(Wout[i0 + j]);
    } else if(b < 520){
      int i0 = (b - 516)*16384;
      for(int j = tid; j < 16384; j += 256) g_w1b[i0 + j] = f2bf(W1[i0 + j]);
    } else {
      for(int j = tid; j < 16384; j += 256) g_w2b[j] = f2bf(W2[j]);
    }
    return;
  }
  int gtid = b*256 + tid;
  if(gtid < 8192) g_D[gtid] = 0;
  else if(gtid < 8448) g_bn2acc[gtid-8192] = 0.f;
  float s0 = 0.f, q0 = 0.f, s1 = 0.f, q1 = 0.f;
  const float* xr = x + (size_t)b*16*TF;
  for(int r = 0; r < 16; r++){
    float v0 = xr[r*TF + tid];
    float v1 = xr[r*TF + 256 + tid];
    s0 += v0; q0 += v0*v0;
    s1 += v1; q1 += v1*v1;
  }
  g_p1s[b*TF + tid]       = s0;
  g_p1q[b*TF + tid]       = q0;
  g_p1s[b*TF + 256 + tid] = s1;
  g_p1q[b*TF + 256 + tid] = q1;
}

// ---------------- K2: bn1 finalize (0,1) | count_src (2..257) ----------------
__global__ __launch_bounds__(256) void k_fin_count(const float* __restrict__ g,
                                                   const float* __restrict__ b,
                                                   const int* __restrict__ e){
  int blk = blockIdx.x, tid = threadIdx.x;
  if(blk < 2){
    int c = blk*256 + tid;
    float s = 0.f, q = 0.f;
    for(int k = 0; k < 512; k++){
      s += g_p1s[k*TF + c];
      q += g_p1q[k*TF + c];
    }
    float m = s/(float)Nn;
    float v = q/(float)Nn - m*m; if(v < 0.f) v = 0.f;
    float rs = rsqrtf(v + BN_EPS);
    float sc = g[c]*rs;
    g_bn1s[c] = sc; g_bn1b[c] = b[c] - m*sc;
  } else {
    int i = (blk-2)*256 + tid;
    if(i < NNZ) atomicAdd(&g_D[e[i]], 1);
  }
}

// ---------------- K3: bn1_apply (bf16) | scan_D ----------------
__global__ __launch_bounds__(256) void k_apply_scan(const float* __restrict__ x){
  int blk = blockIdx.x, tid = threadIdx.x;
  if(blk < 16384){
    int i = blk*256 + tid;
    int c = i & (TF-1);
    int n = i >> 9;
    int t = c >> 4, f = c & 15;
    g_inxb[(t*Nn + n)*Ff + f] = f2bf(x[i]*g_bn1s[c] + g_bn1b[c]);
  } else {
    __shared__ int part[256];
    int s = 0;
    for(int j = 0; j < 32; j++) s += g_D[tid*32 + j];
    part[tid] = s; __syncthreads();
    if(tid == 0){
      int run = 0;
      for(int i = 0; i < 256; i++){ int v = part[i]; part[i] = run; run += v; }
      g_rowptr[Nn] = run;
    }
    __syncthreads();
    int off = part[tid];
    for(int j = 0; j < 32; j++){
      int idx = tid*32 + j;
      g_rowptr[idx] = off; g_cursor[idx] = off;
      off += g_D[idx];
    }
  }
}

// ---------------- K4: GRU (0..511, + q epilogue) | fill_csr (512..639) ----------------
__global__ __launch_bounds__(512, 4) void k_gru_fill(const float* __restrict__ Wih,
                                                     const float* __restrict__ Whh,
                                                     const float* __restrict__ bih,
                                                     const float* __restrict__ bhh,
                                                     const float* __restrict__ Wq,
                                                     const int* __restrict__ e){
  __shared__ __align__(16) short sH[2][16][136];
  int tid = threadIdx.x;
  if(blockIdx.x >= 512){
    int i = (blockIdx.x - 512)*512 + tid;
    if(i < NNZ){
      int pos = atomicAdd(&g_cursor[e[i]], 1);
      g_eidx[pos] = i;
    }
    return;
  }
  int w = tid >> 6, lane = tid & 63;
  int nlo = lane & 15, quad = lane >> 4;
  int n0 = blockIdx.x*16;
  int c = 16*w + nlo;          // this wave's h-channel for this lane

  for(int i = tid; i < 2*16*136; i += 512) (&sH[0][0][0])[i] = 0;

  // Whh fragments: 3 gate tiles x 4 K-chunks = 48 VGPRs
  bf8_t Bh[3][4];
  #pragma unroll
  for(int g = 0; g < 3; g++){
    const float* wr = Whh + (size_t)(g*128 + c)*Hh;
    #pragma unroll
    for(int kk = 0; kk < 4; kk++){
      int k0 = kk*32 + quad*8;
      bf8_t f;
      #pragma unroll
      for(int j = 0; j < 8; j++) f[j] = f2bf(wr[k0 + j]);
      Bh[g][kk] = f;
    }
  }
  // Wih fragments (K=16 padded to 32): 3 tiles = 12 VGPRs
  bf8_t Bx[3];
  #pragma unroll
  for(int g = 0; g < 3; g++){
    const float* wr = Wih + (size_t)(g*128 + c)*Ff;
    bf8_t f;
    #pragma unroll
    for(int j = 0; j < 8; j++){
      int k = quad*8 + j;
      f[j] = (k < Ff) ? f2bf(wr[k]) : (short)0;
    }
    Bx[g] = f;
  }
  float biasR = bih[c]       + bhh[c];
  float biasZ = bih[128 + c] + bhh[128 + c];
  float bihn  = bih[256 + c];
  float bhhn  = bhh[256 + c];
  float hreg[4] = {};

  bf8_t xbuf;
  #pragma unroll
  for(int j = 0; j < 8; j++) xbuf[j] = 0;
  if(quad < 2)
    xbuf = *(const bf8_t*)(g_inxb + ((size_t)(0*Nn + n0 + nlo))*Ff + quad*8);
  __syncthreads();

  int cprow = tid >> 5, cpc4 = tid & 31;   // 512-thread cooperative h-store (b64 each)

  for(int t = 0; t < Tt; t++){
    int cur = t & 1, nxt = cur ^ 1;

    if(t > 0){
      s4_t hv4 = *(const s4_t*)&sH[cur][cprow][cpc4*4];
      *(s4_t*)(g_hsb + ((size_t)(n0 + cprow)*Tt + (t-1))*Hh + cpc4*4) = hv4;
    }
    bf8_t xnbuf;
    #pragma unroll
    for(int j = 0; j < 8; j++) xnbuf[j] = 0;
    if(t+1 < Tt && quad < 2)
      xnbuf = *(const bf8_t*)(g_inxb + ((size_t)((t+1)*Nn + n0 + nlo))*Ff + quad*8);

    f4_t accR, accZ, accN, accX;
    accR[0]=accR[1]=accR[2]=accR[3]=biasR;
    accZ[0]=accZ[1]=accZ[2]=accZ[3]=biasZ;
    accN[0]=accN[1]=accN[2]=accN[3]=0.f;
    accX[0]=accX[1]=accX[2]=accX[3]=bihn;

    accR = MFMA16(xbuf, Bx[0], accR);
    accZ = MFMA16(xbuf, Bx[1], accZ);
    accX = MFMA16(xbuf, Bx[2], accX);

    #pragma unroll
    for(int kk = 0; kk < 4; kk++){
      bf8_t ah = *(const bf8_t*)&sH[cur][nlo][kk*32 + quad*8];
      accR = MFMA16(ah, Bh[0][kk], accR);
      accZ = MFMA16(ah, Bh[1][kk], accZ);
      accN = MFMA16(ah, Bh[2][kk], accN);
    }

    short shi[4];
    #pragma unroll
    for(int rr = 0; rr < 4; rr++){
      float r   = fsigmoid(accR[rr]);
      float z   = fsigmoid(accZ[rr]);
      float hn  = accN[rr] + bhhn;
      float arg = accX[rr] + r*hn;
      float nn  = ftanh(arg);
      float hv  = nn + z*(hreg[rr] - nn);
      hreg[rr] = hv;
      shi[rr] = f2bf(hv);
    }
    #pragma unroll
    for(int rr = 0; rr < 4; rr++)
      sH[nxt][quad*4 + rr][c] = shi[rr];
    bar_lgkm();
    xbuf = xnbuf;
  }
  {
    s4_t hv4 = *(const s4_t*)&sH[0][cprow][cpc4*4];
    *(s4_t*)(g_hsb + ((size_t)(n0 + cprow)*Tt + (Tt-1))*Hh + cpc4*4) = hv4;
  }
  // q epilogue: one 16-col tile per wave (ct = w)
  {
    f4_t qacc; qacc[0]=qacc[1]=qacc[2]=qacc[3]=0.f;
    #pragma unroll
    for(int kk = 0; kk < 4; kk++){
      const float* wr = Wq + (size_t)(16*w + nlo)*Hh + kk*32 + quad*8;
      float4 w0 = *(const float4*)wr;
      float4 w1 = *(const float4*)(wr + 4);
      bf8_t bf;
      bf[0]=f2bf(w0.x); bf[1]=f2bf(w0.y); bf[2]=f2bf(w0.z); bf[3]=f2bf(w0.w);
      bf[4]=f2bf(w1.x); bf[5]=f2bf(w1.y); bf[6]=f2bf(w1.z); bf[7]=f2bf(w1.w);
      bf8_t ah = *(const bf8_t*)&sH[0][nlo][kk*32 + quad*8];
      qacc = MFMA16(ah, bf, qacc);
    }
    #pragma unroll
    for(int rr = 0; rr < 4; rr++)
      g_q[(n0 + quad*4 + rr)*Hh + 16*w + nlo] = qacc[rr];
  }
}

// ---------------- K5: temporal attention middle (bf16 LDS staging, bf16 cmb out) ----------------
__global__ __launch_bounds__(128) void attn_mid(const float* __restrict__ ae,
                                                const float* __restrict__ ab){
  __shared__ __align__(16) short shHs[32][144];
  __shared__ float shQ[128];
  __shared__ float shSc[32];
  __shared__ float shWt[32];
  int n = blockIdx.x, tid = threadIdx.x;
  const int4* src = (const int4*)(g_hsb + (size_t)n*Tt*Hh);
  for(int i = tid; i < 512; i += 128){
    int4 v = src[i];
    int t = i >> 4, h0 = (i & 15) << 3;
    *(int4*)&shHs[t][h0] = v;    // raw bf16 copy, no conversion
  }
  float vq = g_q[n*Hh + tid];
  shQ[tid] = vq;
  __syncthreads();
  {
    int g4 = tid >> 2, l4 = tid & 3;
    float s = 0.f;
    for(int h = l4; h < 128; h += 4) s += shQ[h]*bf2f(shHs[g4][h]);
    s += __shfl_xor(s, 1);
    s += __shfl_xor(s, 2);
    if(l4 == 0) shSc[g4] = s;
  }
  __syncthreads();
  if(tid < 64){
    float v = (tid < 32) ? shSc[tid] : -1e30f;
    float m = v;
    for(int o = 16; o > 0; o >>= 1) m = fmaxf(m, __shfl_xor(m, o));
    float e2 = (tid < 32) ? __expf(v - m) : 0.f;
    float s = e2;
    for(int o = 16; o > 0; o >>= 1) s += __shfl_xor(s, o);
    if(tid < 32) shWt[tid] = e2/s;
  }
  __syncthreads();
  float aev = ae[n], abv = ab[n];
  // bt = exp(-ab*(31-t)) via running product: 2 exps instead of 32
  float btv = __expf(-abv*31.f);
  float fct = __expf(abv);
  float acc = 0.f;
  for(int t = 0; t < 32; t++){
    float mix = shWt[t]*bf2f(shHs[t][tid]);
    float r2  = aev*mix*btv;
    acc += mix + (r2 > 0.f ? r2 : 0.f);
    btv *= fct;
  }
  g_cmbb[n*256 + tid] = f2bf(acc);
  g_cmbb[n*256 + 128 + tid] = f2bf(vq);
}

// ---------------- K6: nf = tanh(cmbb @ Woutb^T) via bf16 MFMA + bn2 partials ----------------
// 256 blocks x 128 thr (2 waves x 16 rows), direct bf16 frags both sides.
__global__ __launch_bounds__(128) void k_gemm_out(float* __restrict__ C2){
  __shared__ float redS[2][128], redQ[2][128];
  int q = blockIdx.x, tid = threadIdx.x;
  int w = tid >> 6, lane = tid & 63;
  int nlo = lane & 15, quad = lane >> 4;
  int arow = q*32 + 16*w + nlo;
  bf8_t a[8];
  #pragma unroll
  for(int kk = 0; kk < 8; kk++)
    a[kk] = *(const bf8_t*)(g_cmbb + (size_t)arow*256 + kk*32 + quad*8);
  #pragma unroll
  for(int ct = 0; ct < 8; ct++){
    f4_t acc; acc[0]=acc[1]=acc[2]=acc[3]=0.f;
    #pragma unroll
    for(int kk = 0; kk < 8; kk++){
      bf8_t bfr = *(const bf8_t*)(g_woutb + (size_t)(16*ct + nlo)*256 + kk*32 + quad*8);
      acc = MFMA16(a[kk], bfr, acc);
    }
    float cs = 0.f, cq2 = 0.f;
    #pragma unroll
    for(int rr = 0; rr < 4; rr++){
      float v = ftanh(acc[rr]);
      int off = (q*32 + 16*w + quad*4 + rr)*Hh + 16*ct + nlo;
      g_nfb[off] = f2bf(v);
      C2[off] = v;
      cs += v; cq2 += v*v;
    }
    cs  += __shfl_xor(cs, 16);  cs  += __shfl_xor(cs, 32);
    cq2 += __shfl_xor(cq2, 16); cq2 += __shfl_xor(cq2, 32);
    if(quad == 0){ redS[w][16*ct + nlo] = cs; redQ[w][16*ct + nlo] = cq2; }
  }
  __syncthreads();
  if(tid < 128){
    float s = redS[0][tid] + redS[1][tid];
    atomicAdd(&g_bn2acc[tid], s);
    float s2 = redQ[0][tid] + redQ[1][tid];
    atomicAdd(&g_bn2acc[128 + tid], s2);
  }
}

// ---------------- K7: egs0->pe1 (0..255, 8 edges/blk, s4 loads) | mm0 MFMA + px1 (256..1279) ----------------
__global__ __launch_bounds__(256) void k_hc1a(const int* __restrict__ e,
                                              const float* __restrict__ g2,
                                              const float* __restrict__ b2){
  int blk = blockIdx.x, tid = threadIdx.x;
  __shared__ float bs[128], bb[128];
  if(tid < 128){
    float s1 = g_bn2acc[tid], s2 = g_bn2acc[128+tid];
    float m = s1/(float)Nn;
    float v = s2/(float)Nn - m*m; if(v < 0.f) v = 0.f;
    float rs = rsqrtf(v + BN_EPS);
    float sc = g2[tid]*rs;
    bs[tid] = sc; bb[tid] = b2[tid] - m*sc;
  }
  if(blk < 256){
    // edge gather: 8 edges per block, 32 lanes x 4 channels each, ushort4 loads
    __shared__ int srcs[8][32];
    __shared__ float w1as[HEADS*Hh];
    for(int i = tid; i < HEADS*Hh; i += 256) w1as[i] = g_w1a[i];
    srcs[tid>>5][tid&31] = e[(blk*8 + (tid>>5)) + (tid&31)*Ee];
    __syncthreads();
    int eidx = tid >> 5, l32 = tid & 31, c0 = l32*4;
    float ac0 = 0.f, ac1 = 0.f, ac2 = 0.f, ac3 = 0.f;
    for(int k = 0; k < 32; k++){
      s4_t v = *(const s4_t*)(g_nfb + (size_t)srcs[eidx][k]*Hh + c0);
      ac0 += bf2f(v[0]); ac1 += bf2f(v[1]); ac2 += bf2f(v[2]); ac3 += bf2f(v[3]);
    }
    float ef0 = ac0*bs[c0]   + 32.f*bb[c0];
    float ef1 = ac1*bs[c0+1] + 32.f*bb[c0+1];
    float ef2 = ac2*bs[c0+2] + 32.f*bb[c0+2];
    float ef3 = ac3*bs[c0+3] + 32.f*bb[c0+3];
    #pragma unroll
    for(int hd = 0; hd < HEADS; hd++){
      const float* wa = &w1as[hd*Hh + c0];
      float p = ef0*wa[0] + ef1*wa[1] + ef2*wa[2] + ef3*wa[3];
      for(int o = 16; o > 0; o >>= 1) p += __shfl_xor(p, o);
      if(l32 == 0) g_pe1[(blk*8 + eidx)*HEADS + hd] = p;
    }
  } else {
    // mm0: xwb[(n, c*4+hd)] = bn2(nf) @ W1^T (bf16 MFMA, pre-converted W1)
    int q = blk - 256;
    int bm = (q >> 3)*64, bn = (q & 7)*64;
    int epi = ((q & 7) == 0);
    __shared__ float w1xs[HEADS*Hh];
    if(epi) for(int i = tid; i < HEADS*Hh; i += 256) w1xs[i] = g_w1x[i];
    __syncthreads();
    int wv = tid >> 6, lane = tid & 63;
    int nlo = lane & 15, quad = lane >> 4;
    int arow = bm + 16*wv + nlo;
    bf8_t a[4]; float av[4][8];
    #pragma unroll
    for(int kk = 0; kk < 4; kk++){
      bf8_t raw = *(const bf8_t*)(g_nfb + (size_t)arow*Hh + kk*32 + quad*8);
      #pragma unroll
      for(int j = 0; j < 8; j++){
        int k = kk*32 + quad*8 + j;
        float t = bf2f(raw[j])*bs[k] + bb[k];
        av[kk][j] = t;
        a[kk][j] = f2bf(t);
      }
    }
    bf8_t Wf[4][4];
    #pragma unroll
    for(int ct = 0; ct < 4; ct++){
      const short* wr0 = g_w1b + (size_t)(bn + 16*ct + nlo)*Hh;
      #pragma unroll
      for(int kk = 0; kk < 4; kk++)
        Wf[ct][kk] = *(const bf8_t*)(wr0 + kk*32 + quad*8);
    }
    f4_t acc[4];
    #pragma unroll
    for(int ct = 0; ct < 4; ct++){ f4_t z4; z4[0]=z4[1]=z4[2]=z4[3]=0.f; acc[ct]=z4; }
    #pragma unroll
    for(int ct = 0; ct < 4; ct++)
      #pragma unroll
      for(int kk = 0; kk < 4; kk++)
        acc[ct] = MFMA16(a[kk], Wf[ct][kk], acc[ct]);
    // store interleaved: col = bn+16ct+nlo -> addr (col&127)*4 + (col>>7)
    #pragma unroll
    for(int ct = 0; ct < 4; ct++){
      int col = bn + 16*ct + nlo;
      int addr = (col & 127)*4 + (col >> 7);
      #pragma unroll
      for(int rr = 0; rr < 4; rr++)
        g_xwb[(size_t)(bm + 16*wv + quad*4 + rr)*512 + addr] = f2bf(acc[ct][rr]);
    }
    if(epi){
      #pragma unroll
      for(int hd = 0; hd < HEADS; hd++){
        float s = 0.f;
        #pragma unroll
        for(int kk = 0; kk < 4; kk++)
          #pragma unroll
          for(int j = 0; j < 8; j++)
            s += av[kk][j]*w1xs[hd*Hh + kk*32 + quad*8 + j];
        s += __shfl_xor(s, 16);
        s += __shfl_xor(s, 32);
        if(quad == 0) g_px1[arow*HEADS + hd] = s;
      }
    }
  }
}

// ---------------- K8: per-src-segment softmax stats + alpha memoization ----------------
__global__ __launch_bounds__(64) void seg_stats1(){
  int n = blockIdx.x, lane = threadIdx.x;
  int start = g_rowptr[n], deg = g_rowptr[n+1] - start;
  float4 px = *(const float4*)&g_px1[n*4];
  float m0 = -1e30f, m1v = -1e30f, m2v = -1e30f, m3v = -1e30f;
  for(int j = lane; j < deg; j += 64){
    int d = g_eidx[start+j] & (Ee-1);
    float4 pe = *(const float4*)&g_pe1[d*4];
    m0  = fmaxf(m0,  lrelu02(px.x + pe.x));
    m1v = fmaxf(m1v, lrelu02(px.y + pe.y));
    m2v = fmaxf(m2v, lrelu02(px.z + pe.z));
    m3v = fmaxf(m3v, lrelu02(px.w + pe.w));
  }
  for(int o = 32; o > 0; o >>= 1){
    m0  = fmaxf(m0,  __shfl_xor(m0,  o));
    m1v = fmaxf(m1v, __shfl_xor(m1v, o));
    m2v = fmaxf(m2v, __shfl_xor(m2v, o));
    m3v = fmaxf(m3v, __shfl_xor(m3v, o));
  }
  float s0 = 0.f, s1 = 0.f, s2 = 0.f, s3 = 0.f;
  for(int j = lane; j < deg; j += 64){
    int d = g_eidx[start+j] & (Ee-1);
    float4 pe = *(const float4*)&g_pe1[d*4];
    s0 += __expf(lrelu02(px.x + pe.x) - m0);
    s1 += __expf(lrelu02(px.y + pe.y) - m1v);
    s2 += __expf(lrelu02(px.z + pe.z) - m2v);
    s3 += __expf(lrelu02(px.w + pe.w) - m3v);
  }
  for(int o = 32; o > 0; o >>= 1){
    s0 += __shfl_xor(s0, o); s1 += __shfl_xor(s1, o);
    s2 += __shfl_xor(s2, o); s3 += __shfl_xor(s3, o);
  }
  float is0 = 1.f/(s0 + 1e-16f), is1 = 1.f/(s1 + 1e-16f);
  float is2 = 1.f/(s2 + 1e-16f), is3 = 1.f/(s3 + 1e-16f);
  // pass 3: memoize alphas per edge (fp32, numerically identical to recompute)
  for(int j = lane; j < deg; j += 64){
    int i = g_eidx[start+j];
    int d = i & (Ee-1);
    float4 pe = *(const float4*)&g_pe1[d*4];
    float4 al;
    al.x = __expf(lrelu02(px.x + pe.x) - m0 )*is0;
    al.y = __expf(lrelu02(px.y + pe.y) - m1v)*is1;
    al.z = __expf(lrelu02(px.z + pe.z) - m2v)*is2;
    al.w = __expf(lrelu02(px.w + pe.w) - m3v)*is3;
    *(float4*)&g_al1[(size_t)i*4] = al;
  }
}

__global__ __launch_bounds__(64) void seg_stats2(){
  int n = blockIdx.x, lane = threadIdx.x;
  int start = g_rowptr[n], deg = g_rowptr[n+1] - start;
  float px = g_pa2[n];
  float m = -1e30f;
  for(int j = lane; j < deg; j += 64){
    int d = g_eidx[start+j] & (Ee-1);
    m = fmaxf(m, lrelu02(px + g_pb2[d]));
  }
  for(int o = 32; o > 0; o >>= 1) m = fmaxf(m, __shfl_xor(m, o));
  float s = 0.f;
  for(int j = lane; j < deg; j += 64){
    int d = g_eidx[start+j] & (Ee-1);
    s += __expf(lrelu02(px + g_pb2[d]) - m);
  }
  for(int o = 32; o > 0; o >>= 1) s += __shfl_xor(s, o);
  float is = 1.f/(s + 1e-16f);
  for(int j = lane; j < deg; j += 64){
    int i = g_eidx[start+j];
    int d = i & (Ee-1);
    g_al2[i] = __expf(lrelu02(px + g_pb2[d]) - m)*is;
  }
}

// ---------------- K9: eout1 (memoized alphas, ushort4 loads) ----------------
__global__ __launch_bounds__(128) void eout1_k(const int* __restrict__ e){
  __shared__ int srcs[32];
  __shared__ __align__(16) float al[32][HEADS];
  int d = blockIdx.x, tid = threadIdx.x;
  if(tid < 32){
    srcs[tid] = e[d + tid*Ee];
    *(float4*)&al[tid][0] = *(const float4*)&g_al1[(size_t)(d + tid*Ee)*4];
  }
  __syncthreads();
  int c = tid;   // 0..127
  float acc[4] = {};
  for(int k = 0; k < 32; k++){
    s4_t v = *(const s4_t*)(g_xwb + (size_t)srcs[k]*512 + c*4);   // 8B: all 4 heads at channel c
    acc[0] += al[k][0]*bf2f(v[0]);
    acc[1] += al[k][1]*bf2f(v[1]);
    acc[2] += al[k][2]*bf2f(v[2]);
    acc[3] += al[k][3]*bf2f(v[3]);
  }
  s4_t ov;
  #pragma unroll
  for(int hd = 0; hd < 4; hd++) ov[hd] = f2bf(acc[hd]*(1.f/32.f));
  *(s4_t*)(g_eoutb + (size_t)d*512 + c*4) = ov;
}

// ---------------- K10: node_out1 (memoized alphas, direct loop) ----------------
__global__ __launch_bounds__(128) void node_out1(const float* __restrict__ bias1){
  int n = blockIdx.x, c = threadIdx.x;
  int start = g_rowptr[n], deg = g_rowptr[n+1] - start;
  float acc = 0.f;
  for(int j = 0; j < deg; j++){
    int i = g_eidx[start+j];
    int d = i & (Ee-1);
    float4 al4 = *(const float4*)&g_al1[(size_t)i*4];
    s4_t v = *(const s4_t*)(g_eoutb + (size_t)d*512 + c*4);
    acc += al4.x*bf2f(v[0]) + al4.y*bf2f(v[1]) + al4.z*bf2f(v[2]) + al4.w*bf2f(v[3]);
  }
  float Dinv = (deg > 0) ? 1.f/(float)deg : 0.f;
  float v = acc*Dinv*0.25f + bias1[c];
  g_x1b[n*Hh + c] = f2bf((v >= 0.f) ? v : 0.2f*v);
}

// ---------------- K11: egs1->pb2 (0..255, 8 edges/blk, s4 loads) | mm2 MFMA + pa2 (256..511) ----------------
__global__ __launch_bounds__(256) void k_hc2a(const int* __restrict__ e){
  int blk = blockIdx.x, tid = threadIdx.x;
  if(blk < 256){
    __shared__ int srcs[8][32];
    __shared__ float w2as[Hh];
    if(tid < 128) w2as[tid] = g_w2a[tid];
    srcs[tid>>5][tid&31] = e[(blk*8 + (tid>>5)) + (tid&31)*Ee];
    __syncthreads();
    int eidx = tid >> 5, l32 = tid & 31, c0 = l32*4;
    float ac0 = 0.f, ac1 = 0.f, ac2 = 0.f, ac3 = 0.f;
    for(int k = 0; k < 32; k++){
      s4_t v = *(const s4_t*)(g_x1b + (size_t)srcs[eidx][k]*Hh + c0);
      ac0 += bf2f(v[0]); ac1 += bf2f(v[1]); ac2 += bf2f(v[2]); ac3 += bf2f(v[3]);
    }
    float p = ac0*w2as[c0] + ac1*w2as[c0+1] + ac2*w2as[c0+2] + ac3*w2as[c0+3];
    for(int o = 16; o > 0; o >>= 1) p += __shfl_xor(p, o);
    if(l32 == 0) g_pb2[blk*8 + eidx] = p;
  } else {
    int q = blk - 256;
    int bm = (q >> 1)*64, bn = (q & 1)*64;
    int epi = ((q & 1) == 0);
    __shared__ float w2xs[Hh];
    if(epi && tid < 128) w2xs[tid] = g_w2x[tid];
    __syncthreads();
    int wv = tid >> 6, lane = tid & 63;
    int nlo = lane & 15, quad = lane >> 4;
    int arow = bm + 16*wv + nlo;
    bf8_t a[4];
    #pragma unroll
    for(int kk = 0; kk < 4; kk++)
      a[kk] = *(const bf8_t*)(g_x1b + (size_t)arow*Hh + kk*32 + quad*8);
    bf8_t Wf[4][4];
    #pragma unroll
    for(int ct = 0; ct < 4; ct++){
      const short* wr0 = g_w2b + (size_t)(bn + 16*ct + nlo)*Hh;
      #pragma unroll
      for(int kk = 0; kk < 4; kk++)
        Wf[ct][kk] = *(const bf8_t*)(wr0 + kk*32 + quad*8);
    }
    f4_t acc[4];
    #pragma unroll
    for(int ct = 0; ct < 4; ct++){ f4_t z4; z4[0]=z4[1]=z4[2]=z4[3]=0.f; acc[ct]=z4; }
    #pragma unroll
    for(int ct = 0; ct < 4; ct++)
      #pragma unroll
      for(int kk = 0; kk < 4; kk++)
        acc[ct] = MFMA16(a[kk], Wf[ct][kk], acc[ct]);
    #pragma unroll
    for(int ct = 0; ct < 4; ct++)
      #pragma unroll
      for(int rr = 0; rr < 4; rr++)
        g_xw2b[(size_t)(bm + 16*wv + quad*4 + rr)*Hh + bn + 16*ct + nlo] = f2bf(acc[ct][rr]);
    if(epi){
      float s = 0.f;
      #pragma unroll
      for(int kk = 0; kk < 4; kk++)
        #pragma unroll
        for(int j = 0; j < 8; j++)
          s += bf2f(a[kk][j])*w2xs[kk*32 + quad*8 + j];
      s += __shfl_xor(s, 16);
      s += __shfl_xor(s, 32);
      if(quad == 0) g_pa2[arow] = s;
    }
  }
}

// ---------------- K13: eout2 (memoized alphas) ----------------
__global__ __launch_bounds__(128) void eout2_k(const int* __restrict__ e){
  __shared__ int srcs[32];
  __shared__ float al[32];
  int d = blockIdx.x, tid = threadIdx.x;
  if(tid < 32){
    srcs[tid] = e[d + tid*Ee];
    al[tid] = g_al2[d + tid*Ee];
  }
  __syncthreads();
  int c = tid;
  float acc = 0.f;
  for(int k = 0; k < 32; k++) acc += al[k]*bf2f(g_xw2b[srcs[k]*Hh + c]);
  g_eout2b[d*Hh + c] = f2bf(acc*(1.f/32.f));
}

// ---------------- K14: node_out2 + final projection (memoized alphas, shuffle reduce) ----------------
__global__ __launch_bounds__(128) void node_out2(const float* __restrict__ bias2,
                                                 const float* __restrict__ Wo, const float* __restrict__ bo,
                                                 float* __restrict__ out_x, float* __restrict__ out_o){
  int n = blockIdx.x, c = threadIdx.x;
  int start = g_rowptr[n], deg = g_rowptr[n+1] - start;
  float acc = 0.f;
  for(int j = 0; j < deg; j++){
    int i = g_eidx[start+j];
    int d = i & (Ee-1);
    float a = g_al2[i];
    acc += a*bf2f(g_eout2b[d*Hh + c]);
  }
  float Dinv = (deg > 0) ? 1.f/(float)deg : 0.f;
  float v = acc*Dinv + bias2[c];
  v = (v >= 0.f) ? v : 0.2f*v;
  out_x[n*Hh + c] = v;
  __shared__ float sh2[2];
  float p = v*Wo[c];
  for(int o = 32; o > 0; o >>= 1) p += __shfl_xor(p, o);
  if((c & 63) == 0) sh2[c >> 6] = p;
  __syncthreads();
  if(c == 0){
    float r = sh2[0] + sh2[1] + bo[0];
    r = (r >= 0.f) ? r : 0.01f*r;
    out_o[n] = r;
  }
}

extern "C" void kernel_launch(void* const* d_in, const int* in_sizes, int n_in,
                              void* d_out, int out_size, void* d_ws, size_t ws_size,
                              hipStream_t stream){
  const float* price = (const float*)d_in[0];
  const int*   e     = (const int*)  d_in[1];
  const float* bn1_g = (const float*)d_in[2];
  const float* bn1_b = (const float*)d_in[3];
  const float* W_ih  = (const float*)d_in[4];
  const float* W_hh  = (const float*)d_in[5];
  const float* b_ih  = (const float*)d_in[6];
  const float* b_hh  = (const float*)d_in[7];
  const float* Wq    = (const float*)d_in[8];
  const float* Wout  = (const float*)d_in[9];
  const float* ae    = (const float*)d_in[10];
  const float* ab    = (const float*)d_in[11];
  const float* bn2_g = (const float*)d_in[12];
  const float* bn2_b = (const float*)d_in[13];
  const float* W1    = (const float*)d_in[14];
  const float* att1  = (const float*)d_in[15];
  const float* bias1 = (const float*)d_in[16];
  const float* W2    = (const float*)d_in[17];
  const float* att2  = (const float*)d_in[18];
  const float* bias2 = (const float*)d_in[19];
  const float* Wo    = (const float*)d_in[20];
  const float* bo    = (const float*)d_in[21];

  float* out_nf = (float*)d_out;
  float* out_x  = out_nf + Nn*Hh;
  float* out_o  = out_nf + 2*Nn*Hh;

  k_pre<<<521, 256, 0, stream>>>(price, W1, att1, W2, att2, Wout);
  k_fin_count<<<258, 256, 0, stream>>>(bn1_g, bn1_b, e);
  k_apply_scan<<<16385, 256, 0, stream>>>(price);
  k_gru_fill<<<640, 512, 0, stream>>>(W_ih, W_hh, b_ih, b_hh, Wq, e);
  attn_mid<<<Nn, 128, 0, stream>>>(ae, ab);
  k_gemm_out<<<256, 128, 0, stream>>>(out_nf);
  k_hc1a<<<1280, 256, 0, stream>>>(e, bn2_g, bn2_b);
  seg_stats1<<<Nn, 64, 0, stream>>>();
  eout1_k<<<Ee, 128, 0, stream>>>(e);
  node_out1<<<Nn, 128, 0, stream>>>(bias1);
  k_hc2a<<<512, 256, 0, stream>>>(e);
  seg_stats2<<<Nn, 64, 0, stream>>>();
  eout2_k<<<Ee, 128, 0, stream>>>(e);
  node_out2<<<Nn, 128, 0, stream>>>(bias2, Wo, bo, out_x, out_o);

  (void)in_sizes; (void)n_in; (void)out_size; (void)d_ws; (void)ws_size;
}

// Round 8
// 315.572 us; speedup vs baseline: 1.1191x; 1.1191x over previous
//
#include <hip/hip_runtime.h>
#include <hip/hip_bf16.h>

#define Nn 8192
#define Tt 32
#define Ff 16
#define Hh 128
#define HEADS 4
#define Ee 2048
#define NNZ 65536
#define TF (Tt*Ff)       // 512
#define BN_EPS 1e-5f

// All float tensors are float32 per the reference.

typedef __attribute__((ext_vector_type(8))) short bf8_t;   // 8 bf16 lanes (4 VGPRs)
typedef __attribute__((ext_vector_type(4))) float f4_t;
typedef __attribute__((ext_vector_type(4))) short s4_t;
#define MFMA16(a,b,c) __builtin_amdgcn_mfma_f32_16x16x32_bf16(a,b,c,0,0,0)

__device__ __forceinline__ short f2bf(float v){
  union { __hip_bfloat16 h; short s; } u;
  u.h = __float2bfloat16(v);
  return u.s;
}
__device__ __forceinline__ float bf2f(short s){
  union { __hip_bfloat16 h; short s2; } u;
  u.s2 = s;
  return __bfloat162float(u.h);
}
__device__ __forceinline__ float fsigmoid(float x){
  return __builtin_amdgcn_rcpf(1.f + __expf(-x));
}
__device__ __forceinline__ float ftanh(float x){
  return 1.f - 2.f*__builtin_amdgcn_rcpf(__expf(2.f*x) + 1.f);
}
__device__ __forceinline__ float lrelu02(float x){ return (x >= 0.f) ? x : 0.2f*x; }
// Barrier that waits only on LDS ops (global stores/prefetch stay in flight).
__device__ __forceinline__ void bar_lgkm(){
  asm volatile("s_waitcnt lgkmcnt(0)\n\ts_barrier" ::: "memory");
}

// ---------------- static scratch (fully rewritten every call) ----------------
__device__ __align__(16) short g_inxb[Nn*TF];   // bn1 output bf16, (T, N, F)
__device__ __align__(16) short g_hsb[Nn*Tt*Hh]; // GRU hidden states bf16, (N, T, H)
__device__ float  g_q[Nn*Hh];            // query = h31 @ Wq^T (gru epilogue)
__device__ __align__(16) short g_cmbb[Nn*2*Hh]; // [mixsum | q] per node, bf16
__device__ __align__(16) short g_nfb[Nn*Hh];     // nf bf16
__device__ __align__(16) short g_woutb[Hh*256];  // Wout as bf16
__device__ __align__(16) short g_w1b[4*Hh*Hh];   // W1 as bf16
__device__ __align__(16) short g_w2b[Hh*Hh];     // W2 as bf16
__device__ __align__(16) short g_xwb[Nn*4*Hh];   // bn2(nf)@W1^T bf16, layout (n, c*4+hd)
__device__ __align__(16) short g_x1b[Nn*Hh];     // layer-1 node out, bf16
__device__ __align__(16) short g_xw2b[Nn*Hh];    // x1 @ W2^T, bf16
__device__ __align__(16) short g_eoutb[Ee*4*Hh]; // edge agg 1 bf16, layout (d, c*4+hd)
__device__ __align__(16) short g_eout2b[Ee*Hh];  // edge agg 2, bf16
__device__ float  g_px1[Nn*HEADS];       // att dots
__device__ float  g_pe1[Ee*HEADS];
__device__ float  g_pa2[Nn];
__device__ float  g_pb2[Ee];
__device__ __align__(16) float g_al1[NNZ*HEADS]; // memoized softmax alphas, layer 1
__device__ float  g_al2[NNZ];                    // layer 2
__device__ float  g_w1x[HEADS*Hh];       // precomputed W^T-att folds
__device__ float  g_w1a[HEADS*Hh];
__device__ float  g_w2x[Hh];
__device__ float  g_w2a[Hh];
__device__ float  g_p1s[512*TF];         // bn1 partials
__device__ float  g_p1q[512*TF];
__device__ float  g_bn1acc[2*TF];        // [0:512) col sums, [512:1024) sumsq (atomic)
__device__ float  g_bn2acc[256];         // [0:128) col sums of nf, [128:256) sumsq
__device__ int    g_D[Nn];
__device__ int    g_rowptr[Nn+1];
__device__ int    g_cursor[Nn];
__device__ int    g_eidx[NNZ];

// ---------------- K1: bn1 partials + zero accums (0..511) | w-folds (512,513) | bf16 weight converts (514..520) ----------------
__global__ __launch_bounds__(256) void k_pre(const float* __restrict__ x,
                                             const float* __restrict__ W1,
                                             const float* __restrict__ att1,
                                             const float* __restrict__ W2,
                                             const float* __restrict__ att2,
                                             const float* __restrict__ Wout){
  int b = blockIdx.x, tid = threadIdx.x;
  if(b >= 512){
    if(b == 512){
      // w1x[hd,k] = sum_c W1[(hd*128+c)*128+k]*att1[hd*256+c]; w1a likewise with +128
      for(int p = 0; p < 2; p++){
        int idx = p*256 + tid;           // 512 entries
        int hd = idx >> 7, k = idx & 127;
        float sx = 0.f, sa = 0.f;
        for(int c = 0; c < 128; c++){
          float wv = W1[(hd*128 + c)*128 + k];
          sx += wv*att1[hd*256 + c];
          sa += wv*att1[hd*256 + 128 + c];
        }
        g_w1x[idx] = sx; g_w1a[idx] = sa;
      }
    } else if(b == 513){
      int k = tid & 127;
      if(tid < 128){
        float s = 0.f;
        for(int c = 0; c < 128; c++) s += W2[c*128 + k]*att2[c];
        g_w2x[k] = s;
      } else {
        float s = 0.f;
        for(int c = 0; c < 128; c++) s += W2[c*128 + k]*att2[128 + c];
        g_w2a[k] = s;
      }
    } else if(b < 516){
      int i0 = (b - 514)*16384;
      for(int j = tid; j < 16384; j += 256) g_woutb[i0 + j] = f2bf(Wout[i0 + j]);
    } else if(b < 520){
      int i0 = (b - 516)*16384;
      for(int j = tid; j < 16384; j += 256) g_w1b[i0 + j] = f2bf(W1[i0 + j]);
    } else {
      for(int j = tid; j < 16384; j += 256) g_w2b[j] = f2bf(W2[j]);
    }
    return;
  }
  int gtid = b*256 + tid;
  if(gtid < 8192) g_D[gtid] = 0;
  else if(gtid < 8448) g_bn2acc[gtid-8192] = 0.f;
  else if(gtid < 9472) g_bn1acc[gtid-8448] = 0.f;
  float s0 = 0.f, q0 = 0.f, s1 = 0.f, q1 = 0.f;
  const float* xr = x + (size_t)b*16*TF;
  for(int r = 0; r < 16; r++){
    float v0 = xr[r*TF + tid];
    float v1 = xr[r*TF + 256 + tid];
    s0 += v0; q0 += v0*v0;
    s1 += v1; q1 += v1*v1;
  }
  g_p1s[b*TF + tid]       = s0;
  g_p1q[b*TF + tid]       = q0;
  g_p1s[b*TF + 256 + tid] = s1;
  g_p1q[b*TF + 256 + tid] = q1;
}

// ---------------- K2: bn1 partial-reduce (0..63, 8 k-rows each, atomic) | count_src (64..319) ----------------
// Replaces the old 2-block / 512-deep serial finalize (4MB through 2 CUs' L2 path).
__global__ __launch_bounds__(256) void k_fin_count(const int* __restrict__ e){
  int blk = blockIdx.x, tid = threadIdx.x;
  if(blk < 64){
    int c = tid;
    float s0 = 0.f, q0 = 0.f, s1 = 0.f, q1 = 0.f;
    #pragma unroll
    for(int kk = 0; kk < 8; kk++){
      int k = blk*8 + kk;
      s0 += g_p1s[k*TF + c];       q0 += g_p1q[k*TF + c];
      s1 += g_p1s[k*TF + 256 + c]; q1 += g_p1q[k*TF + 256 + c];
    }
    atomicAdd(&g_bn1acc[c], s0);        atomicAdd(&g_bn1acc[TF + c], q0);
    atomicAdd(&g_bn1acc[256 + c], s1);  atomicAdd(&g_bn1acc[TF + 256 + c], q1);
  } else {
    int i = (blk-64)*256 + tid;
    if(i < NNZ) atomicAdd(&g_D[e[i]], 1);
  }
}

// ---------------- K3: bn1_apply (LDS-transposed, contiguous writes) | scan_D (blk 256) ----------------
// Old version wrote 32B chunks at 256KB stride (t-major scatter). New: 32 nodes/block,
// LDS-staged transpose -> per-t 1KB contiguous stores. bn1 scale/bias finalized
// redundantly per block from g_bn1acc (4KB, L2-broadcast).
__global__ __launch_bounds__(256) void k_apply_scan(const float* __restrict__ x,
                                                    const float* __restrict__ g,
                                                    const float* __restrict__ b){
  int blk = blockIdx.x, tid = threadIdx.x;
  if(blk < 256){
    __shared__ float bs[TF], bb[TF];
    __shared__ __align__(16) short sx[32][520];
    for(int c = tid; c < TF; c += 256){
      float s = g_bn1acc[c], q = g_bn1acc[TF + c];
      float m = s/(float)Nn;
      float v = q/(float)Nn - m*m; if(v < 0.f) v = 0.f;
      float rs = rsqrtf(v + BN_EPS);
      float sc = g[c]*rs;
      bs[c] = sc; bb[c] = b[c] - m*sc;
    }
    __syncthreads();
    int n0 = blk*32;
    const float4* xp = (const float4*)(x + (size_t)n0*TF);
    #pragma unroll
    for(int k = 0; k < 16; k++){
      int f4i = tid + k*256;           // 4096 float4 per 32-node chunk
      float4 v4 = xp[f4i];
      int r = f4i >> 7, c0 = (f4i & 127)*4;
      s4_t o;
      o[0] = f2bf(v4.x*bs[c0]   + bb[c0]);
      o[1] = f2bf(v4.y*bs[c0+1] + bb[c0+1]);
      o[2] = f2bf(v4.z*bs[c0+2] + bb[c0+2]);
      o[3] = f2bf(v4.w*bs[c0+3] + bb[c0+3]);
      *(s4_t*)&sx[r][c0] = o;
    }
    __syncthreads();
    #pragma unroll
    for(int ti = 0; ti < 16; ti++){
      int t = ti*2 + (tid >> 7);
      int u = tid & 127;
      int r = u >> 2, f0 = (u & 3)*4;
      s4_t o = *(const s4_t*)&sx[r][t*16 + f0];
      *(s4_t*)(g_inxb + ((size_t)t*Nn + n0 + r)*Ff + f0) = o;
    }
  } else {
    __shared__ int part[256];
    int s = 0;
    for(int j = 0; j < 32; j++) s += g_D[tid*32 + j];
    part[tid] = s; __syncthreads();
    if(tid == 0){
      int run = 0;
      for(int i = 0; i < 256; i++){ int v = part[i]; part[i] = run; run += v; }
      g_rowptr[Nn] = run;
    }
    __syncthreads();
    int off = part[tid];
    for(int j = 0; j < 32; j++){
      int idx = tid*32 + j;
      g_rowptr[idx] = off; g_cursor[idx] = off;
      off += g_D[idx];
    }
  }
}

// ---------------- K4: GRU (0..511, + q epilogue) | fill_csr (512..639) ----------------
__global__ __launch_bounds__(512, 4) void k_gru_fill(const float* __restrict__ Wih,
                                                     const float* __restrict__ Whh,
                                                     const float* __restrict__ bih,
                                                     const float* __restrict__ bhh,
                                                     const float* __restrict__ Wq,
                                                     const int* __restrict__ e){
  __shared__ __align__(16) short sH[2][16][136];
  int tid = threadIdx.x;
  if(blockIdx.x >= 512){
    int i = (blockIdx.x - 512)*512 + tid;
    if(i < NNZ){
      int pos = atomicAdd(&g_cursor[e[i]], 1);
      g_eidx[pos] = i;
    }
    return;
  }
  int w = tid >> 6, lane = tid & 63;
  int nlo = lane & 15, quad = lane >> 4;
  int n0 = blockIdx.x*16;
  int c = 16*w + nlo;          // this wave's h-channel for this lane

  for(int i = tid; i < 2*16*136; i += 512) (&sH[0][0][0])[i] = 0;

  // Whh fragments: 3 gate tiles x 4 K-chunks = 48 VGPRs
  bf8_t Bh[3][4];
  #pragma unroll
  for(int g = 0; g < 3; g++){
    const float* wr = Whh + (size_t)(g*128 + c)*Hh;
    #pragma unroll
    for(int kk = 0; kk < 4; kk++){
      int k0 = kk*32 + quad*8;
      bf8_t f;
      #pragma unroll
      for(int j = 0; j < 8; j++) f[j] = f2bf(wr[k0 + j]);
      Bh[g][kk] = f;
    }
  }
  // Wih fragments (K=16 padded to 32): 3 tiles = 12 VGPRs
  bf8_t Bx[3];
  #pragma unroll
  for(int g = 0; g < 3; g++){
    const float* wr = Wih + (size_t)(g*128 + c)*Ff;
    bf8_t f;
    #pragma unroll
    for(int j = 0; j < 8; j++){
      int k = quad*8 + j;
      f[j] = (k < Ff) ? f2bf(wr[k]) : (short)0;
    }
    Bx[g] = f;
  }
  float biasR = bih[c]       + bhh[c];
  float biasZ = bih[128 + c] + bhh[128 + c];
  float bihn  = bih[256 + c];
  float bhhn  = bhh[256 + c];
  float hreg[4] = {};

  bf8_t xbuf;
  #pragma unroll
  for(int j = 0; j < 8; j++) xbuf[j] = 0;
  if(quad < 2)
    xbuf = *(const bf8_t*)(g_inxb + ((size_t)(0*Nn + n0 + nlo))*Ff + quad*8);
  __syncthreads();

  int cprow = tid >> 5, cpc4 = tid & 31;   // 512-thread cooperative h-store (b64 each)

  for(int t = 0; t < Tt; t++){
    int cur = t & 1, nxt = cur ^ 1;

    if(t > 0){
      s4_t hv4 = *(const s4_t*)&sH[cur][cprow][cpc4*4];
      *(s4_t*)(g_hsb + ((size_t)(n0 + cprow)*Tt + (t-1))*Hh + cpc4*4) = hv4;
    }
    bf8_t xnbuf;
    #pragma unroll
    for(int j = 0; j < 8; j++) xnbuf[j] = 0;
    if(t+1 < Tt && quad < 2)
      xnbuf = *(const bf8_t*)(g_inxb + ((size_t)((t+1)*Nn + n0 + nlo))*Ff + quad*8);

    f4_t accR, accZ, accN, accX;
    accR[0]=accR[1]=accR[2]=accR[3]=biasR;
    accZ[0]=accZ[1]=accZ[2]=accZ[3]=biasZ;
    accN[0]=accN[1]=accN[2]=accN[3]=0.f;
    accX[0]=accX[1]=accX[2]=accX[3]=bihn;

    accR = MFMA16(xbuf, Bx[0], accR);
    accZ = MFMA16(xbuf, Bx[1], accZ);
    accX = MFMA16(xbuf, Bx[2], accX);

    #pragma unroll
    for(int kk = 0; kk < 4; kk++){
      bf8_t ah = *(const bf8_t*)&sH[cur][nlo][kk*32 + quad*8];
      accR = MFMA16(ah, Bh[0][kk], accR);
      accZ = MFMA16(ah, Bh[1][kk], accZ);
      accN = MFMA16(ah, Bh[2][kk], accN);
    }

    short shi[4];
    #pragma unroll
    for(int rr = 0; rr < 4; rr++){
      float r   = fsigmoid(accR[rr]);
      float z   = fsigmoid(accZ[rr]);
      float hn  = accN[rr] + bhhn;
      float arg = accX[rr] + r*hn;
      float nn  = ftanh(arg);
      float hv  = nn + z*(hreg[rr] - nn);
      hreg[rr] = hv;
      shi[rr] = f2bf(hv);
    }
    #pragma unroll
    for(int rr = 0; rr < 4; rr++)
      sH[nxt][quad*4 + rr][c] = shi[rr];
    bar_lgkm();
    xbuf = xnbuf;
  }
  {
    s4_t hv4 = *(const s4_t*)&sH[0][cprow][cpc4*4];
    *(s4_t*)(g_hsb + ((size_t)(n0 + cprow)*Tt + (Tt-1))*Hh + cpc4*4) = hv4;
  }
  // q epilogue: one 16-col tile per wave (ct = w)
  {
    f4_t qacc; qacc[0]=qacc[1]=qacc[2]=qacc[3]=0.f;
    #pragma unroll
    for(int kk = 0; kk < 4; kk++){
      const float* wr = Wq + (size_t)(16*w + nlo)*Hh + kk*32 + quad*8;
      float4 w0 = *(const float4*)wr;
      float4 w1 = *(const float4*)(wr + 4);
      bf8_t bf;
      bf[0]=f2bf(w0.x); bf[1]=f2bf(w0.y); bf[2]=f2bf(w0.z); bf[3]=f2bf(w0.w);
      bf[4]=f2bf(w1.x); bf[5]=f2bf(w1.y); bf[6]=f2bf(w1.z); bf[7]=f2bf(w1.w);
      bf8_t ah = *(const bf8_t*)&sH[0][nlo][kk*32 + quad*8];
      qacc = MFMA16(ah, bf, qacc);
    }
    #pragma unroll
    for(int rr = 0; rr < 4; rr++)
      g_q[(n0 + quad*4 + rr)*Hh + 16*w + nlo] = qacc[rr];
  }
}

// ---------------- K5: temporal attention middle (bf16 LDS staging, bf16 cmb out) ----------------
__global__ __launch_bounds__(128) void attn_mid(const float* __restrict__ ae,
                                                const float* __restrict__ ab){
  __shared__ __align__(16) short shHs[32][144];
  __shared__ float shQ[128];
  __shared__ float shSc[32];
  __shared__ float shWt[32];
  int n = blockIdx.x, tid = threadIdx.x;
  const int4* src = (const int4*)(g_hsb + (size_t)n*Tt*Hh);
  for(int i = tid; i < 512; i += 128){
    int4 v = src[i];
    int t = i >> 4, h0 = (i & 15) << 3;
    *(int4*)&shHs[t][h0] = v;    // raw bf16 copy, no conversion
  }
  float vq = g_q[n*Hh + tid];
  shQ[tid] = vq;
  __syncthreads();
  {
    int g4 = tid >> 2, l4 = tid & 3;
    float s = 0.f;
    for(int h = l4; h < 128; h += 4) s += shQ[h]*bf2f(shHs[g4][h]);
    s += __shfl_xor(s, 1);
    s += __shfl_xor(s, 2);
    if(l4 == 0) shSc[g4] = s;
  }
  __syncthreads();
  if(tid < 64){
    float v = (tid < 32) ? shSc[tid] : -1e30f;
    float m = v;
    for(int o = 16; o > 0; o >>= 1) m = fmaxf(m, __shfl_xor(m, o));
    float e2 = (tid < 32) ? __expf(v - m) : 0.f;
    float s = e2;
    for(int o = 16; o > 0; o >>= 1) s += __shfl_xor(s, o);
    if(tid < 32) shWt[tid] = e2/s;
  }
  __syncthreads();
  float aev = ae[n], abv = ab[n];
  // bt = exp(-ab*(31-t)) via running product: 2 exps instead of 32
  float btv = __expf(-abv*31.f);
  float fct = __expf(abv);
  float acc = 0.f;
  for(int t = 0; t < 32; t++){
    float mix = shWt[t]*bf2f(shHs[t][tid]);
    float r2  = aev*mix*btv;
    acc += mix + (r2 > 0.f ? r2 : 0.f);
    btv *= fct;
  }
  g_cmbb[n*256 + tid] = f2bf(acc);
  g_cmbb[n*256 + 128 + tid] = f2bf(vq);
}

// ---------------- K6: nf = tanh(cmbb @ Woutb^T) via bf16 MFMA + bn2 partials ----------------
// 256 blocks x 128 thr (2 waves x 16 rows), direct bf16 frags both sides.
__global__ __launch_bounds__(128) void k_gemm_out(float* __restrict__ C2){
  __shared__ float redS[2][128], redQ[2][128];
  int q = blockIdx.x, tid = threadIdx.x;
  int w = tid >> 6, lane = tid & 63;
  int nlo = lane & 15, quad = lane >> 4;
  int arow = q*32 + 16*w + nlo;
  bf8_t a[8];
  #pragma unroll
  for(int kk = 0; kk < 8; kk++)
    a[kk] = *(const bf8_t*)(g_cmbb + (size_t)arow*256 + kk*32 + quad*8);
  #pragma unroll
  for(int ct = 0; ct < 8; ct++){
    f4_t acc; acc[0]=acc[1]=acc[2]=acc[3]=0.f;
    #pragma unroll
    for(int kk = 0; kk < 8; kk++){
      bf8_t bfr = *(const bf8_t*)(g_woutb + (size_t)(16*ct + nlo)*256 + kk*32 + quad*8);
      acc = MFMA16(a[kk], bfr, acc);
    }
    float cs = 0.f, cq2 = 0.f;
    #pragma unroll
    for(int rr = 0; rr < 4; rr++){
      float v = ftanh(acc[rr]);
      int off = (q*32 + 16*w + quad*4 + rr)*Hh + 16*ct + nlo;
      g_nfb[off] = f2bf(v);
      C2[off] = v;
      cs += v; cq2 += v*v;
    }
    cs  += __shfl_xor(cs, 16);  cs  += __shfl_xor(cs, 32);
    cq2 += __shfl_xor(cq2, 16); cq2 += __shfl_xor(cq2, 32);
    if(quad == 0){ redS[w][16*ct + nlo] = cs; redQ[w][16*ct + nlo] = cq2; }
  }
  __syncthreads();
  if(tid < 128){
    float s = redS[0][tid] + redS[1][tid];
    atomicAdd(&g_bn2acc[tid], s);
    float s2 = redQ[0][tid] + redQ[1][tid];
    atomicAdd(&g_bn2acc[128 + tid], s2);
  }
}

// ---------------- K7: egs0->pe1 (0..255, 8 edges/blk, s4 loads) | mm0 MFMA + px1 (256..1279) ----------------
__global__ __launch_bounds__(256) void k_hc1a(const int* __restrict__ e,
                                              const float* __restrict__ g2,
                                              const float* __restrict__ b2){
  int blk = blockIdx.x, tid = threadIdx.x;
  __shared__ float bs[128], bb[128];
  if(tid < 128){
    float s1 = g_bn2acc[tid], s2 = g_bn2acc[128+tid];
    float m = s1/(float)Nn;
    float v = s2/(float)Nn - m*m; if(v < 0.f) v = 0.f;
    float rs = rsqrtf(v + BN_EPS);
    float sc = g2[tid]*rs;
    bs[tid] = sc; bb[tid] = b2[tid] - m*sc;
  }
  if(blk < 256){
    // edge gather: 8 edges per block, 32 lanes x 4 channels each, ushort4 loads
    __shared__ int srcs[8][32];
    __shared__ float w1as[HEADS*Hh];
    for(int i = tid; i < HEADS*Hh; i += 256) w1as[i] = g_w1a[i];
    srcs[tid>>5][tid&31] = e[(blk*8 + (tid>>5)) + (tid&31)*Ee];
    __syncthreads();
    int eidx = tid >> 5, l32 = tid & 31, c0 = l32*4;
    float ac0 = 0.f, ac1 = 0.f, ac2 = 0.f, ac3 = 0.f;
    for(int k = 0; k < 32; k++){
      s4_t v = *(const s4_t*)(g_nfb + (size_t)srcs[eidx][k]*Hh + c0);
      ac0 += bf2f(v[0]); ac1 += bf2f(v[1]); ac2 += bf2f(v[2]); ac3 += bf2f(v[3]);
    }
    float ef0 = ac0*bs[c0]   + 32.f*bb[c0];
    float ef1 = ac1*bs[c0+1] + 32.f*bb[c0+1];
    float ef2 = ac2*bs[c0+2] + 32.f*bb[c0+2];
    float ef3 = ac3*bs[c0+3] + 32.f*bb[c0+3];
    #pragma unroll
    for(int hd = 0; hd < HEADS; hd++){
      const float* wa = &w1as[hd*Hh + c0];
      float p = ef0*wa[0] + ef1*wa[1] + ef2*wa[2] + ef3*wa[3];
      for(int o = 16; o > 0; o >>= 1) p += __shfl_xor(p, o);
      if(l32 == 0) g_pe1[(blk*8 + eidx)*HEADS + hd] = p;
    }
  } else {
    // mm0: xwb[(n, c*4+hd)] = bn2(nf) @ W1^T (bf16 MFMA, pre-converted W1)
    int q = blk - 256;
    int bm = (q >> 3)*64, bn = (q & 7)*64;
    int epi = ((q & 7) == 0);
    __shared__ float w1xs[HEADS*Hh];
    if(epi) for(int i = tid; i < HEADS*Hh; i += 256) w1xs[i] = g_w1x[i];
    __syncthreads();
    int wv = tid >> 6, lane = tid & 63;
    int nlo = lane & 15, quad = lane >> 4;
    int arow = bm + 16*wv + nlo;
    bf8_t a[4]; float av[4][8];
    #pragma unroll
    for(int kk = 0; kk < 4; kk++){
      bf8_t raw = *(const bf8_t*)(g_nfb + (size_t)arow*Hh + kk*32 + quad*8);
      #pragma unroll
      for(int j = 0; j < 8; j++){
        int k = kk*32 + quad*8 + j;
        float t = bf2f(raw[j])*bs[k] + bb[k];
        av[kk][j] = t;
        a[kk][j] = f2bf(t);
      }
    }
    bf8_t Wf[4][4];
    #pragma unroll
    for(int ct = 0; ct < 4; ct++){
      const short* wr0 = g_w1b + (size_t)(bn + 16*ct + nlo)*Hh;
      #pragma unroll
      for(int kk = 0; kk < 4; kk++)
        Wf[ct][kk] = *(const bf8_t*)(wr0 + kk*32 + quad*8);
    }
    f4_t acc[4];
    #pragma unroll
    for(int ct = 0; ct < 4; ct++){ f4_t z4; z4[0]=z4[1]=z4[2]=z4[3]=0.f; acc[ct]=z4; }
    #pragma unroll
    for(int ct = 0; ct < 4; ct++)
      #pragma unroll
      for(int kk = 0; kk < 4; kk++)
        acc[ct] = MFMA16(a[kk], Wf[ct][kk], acc[ct]);
    // store interleaved: col = bn+16ct+nlo -> addr (col&127)*4 + (col>>7)
    #pragma unroll
    for(int ct = 0; ct < 4; ct++){
      int col = bn + 16*ct + nlo;
      int addr = (col & 127)*4 + (col >> 7);
      #pragma unroll
      for(int rr = 0; rr < 4; rr++)
        g_xwb[(size_t)(bm + 16*wv + quad*4 + rr)*512 + addr] = f2bf(acc[ct][rr]);
    }
    if(epi){
      #pragma unroll
      for(int hd = 0; hd < HEADS; hd++){
        float s = 0.f;
        #pragma unroll
        for(int kk = 0; kk < 4; kk++)
          #pragma unroll
          for(int j = 0; j < 8; j++)
            s += av[kk][j]*w1xs[hd*Hh + kk*32 + quad*8 + j];
        s += __shfl_xor(s, 16);
        s += __shfl_xor(s, 32);
        if(quad == 0) g_px1[arow*HEADS + hd] = s;
      }
    }
  }
}

// ---------------- K8: per-src-segment softmax stats + alpha memoization ----------------
__global__ __launch_bounds__(64) void seg_stats1(){
  int n = blockIdx.x, lane = threadIdx.x;
  int start = g_rowptr[n], deg = g_rowptr[n+1] - start;
  float4 px = *(const float4*)&g_px1[n*4];
  float m0 = -1e30f, m1v = -1e30f, m2v = -1e30f, m3v = -1e30f;
  for(int j = lane; j < deg; j += 64){
    int d = g_eidx[start+j] & (Ee-1);
    float4 pe = *(const float4*)&g_pe1[d*4];
    m0  = fmaxf(m0,  lrelu02(px.x + pe.x));
    m1v = fmaxf(m1v, lrelu02(px.y + pe.y));
    m2v = fmaxf(m2v, lrelu02(px.z + pe.z));
    m3v = fmaxf(m3v, lrelu02(px.w + pe.w));
  }
  for(int o = 32; o > 0; o >>= 1){
    m0  = fmaxf(m0,  __shfl_xor(m0,  o));
    m1v = fmaxf(m1v, __shfl_xor(m1v, o));
    m2v = fmaxf(m2v, __shfl_xor(m2v, o));
    m3v = fmaxf(m3v, __shfl_xor(m3v, o));
  }
  float s0 = 0.f, s1 = 0.f, s2 = 0.f, s3 = 0.f;
  for(int j = lane; j < deg; j += 64){
    int d = g_eidx[start+j] & (Ee-1);
    float4 pe = *(const float4*)&g_pe1[d*4];
    s0 += __expf(lrelu02(px.x + pe.x) - m0);
    s1 += __expf(lrelu02(px.y + pe.y) - m1v);
    s2 += __expf(lrelu02(px.z + pe.z) - m2v);
    s3 += __expf(lrelu02(px.w + pe.w) - m3v);
  }
  for(int o = 32; o > 0; o >>= 1){
    s0 += __shfl_xor(s0, o); s1 += __shfl_xor(s1, o);
    s2 += __shfl_xor(s2, o); s3 += __shfl_xor(s3, o);
  }
  float is0 = 1.f/(s0 + 1e-16f), is1 = 1.f/(s1 + 1e-16f);
  float is2 = 1.f/(s2 + 1e-16f), is3 = 1.f/(s3 + 1e-16f);
  // pass 3: memoize alphas per edge (fp32, numerically identical to recompute)
  for(int j = lane; j < deg; j += 64){
    int i = g_eidx[start+j];
    int d = i & (Ee-1);
    float4 pe = *(const float4*)&g_pe1[d*4];
    float4 al;
    al.x = __expf(lrelu02(px.x + pe.x) - m0 )*is0;
    al.y = __expf(lrelu02(px.y + pe.y) - m1v)*is1;
    al.z = __expf(lrelu02(px.z + pe.z) - m2v)*is2;
    al.w = __expf(lrelu02(px.w + pe.w) - m3v)*is3;
    *(float4*)&g_al1[(size_t)i*4] = al;
  }
}

__global__ __launch_bounds__(64) void seg_stats2(){
  int n = blockIdx.x, lane = threadIdx.x;
  int start = g_rowptr[n], deg = g_rowptr[n+1] - start;
  float px = g_pa2[n];
  float m = -1e30f;
  for(int j = lane; j < deg; j += 64){
    int d = g_eidx[start+j] & (Ee-1);
    m = fmaxf(m, lrelu02(px + g_pb2[d]));
  }
  for(int o = 32; o > 0; o >>= 1) m = fmaxf(m, __shfl_xor(m, o));
  float s = 0.f;
  for(int j = lane; j < deg; j += 64){
    int d = g_eidx[start+j] & (Ee-1);
    s += __expf(lrelu02(px + g_pb2[d]) - m);
  }
  for(int o = 32; o > 0; o >>= 1) s += __shfl_xor(s, o);
  float is = 1.f/(s + 1e-16f);
  for(int j = lane; j < deg; j += 64){
    int i = g_eidx[start+j];
    int d = i & (Ee-1);
    g_al2[i] = __expf(lrelu02(px + g_pb2[d]) - m)*is;
  }
}

// ---------------- K9: eout1 (memoized alphas, ushort4 loads) ----------------
__global__ __launch_bounds__(128) void eout1_k(const int* __restrict__ e){
  __shared__ int srcs[32];
  __shared__ __align__(16) float al[32][HEADS];
  int d = blockIdx.x, tid = threadIdx.x;
  if(tid < 32){
    srcs[tid] = e[d + tid*Ee];
    *(float4*)&al[tid][0] = *(const float4*)&g_al1[(size_t)(d + tid*Ee)*4];
  }
  __syncthreads();
  int c = tid;   // 0..127
  float acc[4] = {};
  for(int k = 0; k < 32; k++){
    s4_t v = *(const s4_t*)(g_xwb + (size_t)srcs[k]*512 + c*4);   // 8B: all 4 heads at channel c
    acc[0] += al[k][0]*bf2f(v[0]);
    acc[1] += al[k][1]*bf2f(v[1]);
    acc[2] += al[k][2]*bf2f(v[2]);
    acc[3] += al[k][3]*bf2f(v[3]);
  }
  s4_t ov;
  #pragma unroll
  for(int hd = 0; hd < 4; hd++) ov[hd] = f2bf(acc[hd]*(1.f/32.f));
  *(s4_t*)(g_eoutb + (size_t)d*512 + c*4) = ov;
}

// ---------------- K10: node_out1 (memoized alphas, direct loop) ----------------
__global__ __launch_bounds__(128) void node_out1(const float* __restrict__ bias1){
  int n = blockIdx.x, c = threadIdx.x;
  int start = g_rowptr[n], deg = g_rowptr[n+1] - start;
  float acc = 0.f;
  for(int j = 0; j < deg; j++){
    int i = g_eidx[start+j];
    int d = i & (Ee-1);
    float4 al4 = *(const float4*)&g_al1[(size_t)i*4];
    s4_t v = *(const s4_t*)(g_eoutb + (size_t)d*512 + c*4);
    acc += al4.x*bf2f(v[0]) + al4.y*bf2f(v[1]) + al4.z*bf2f(v[2]) + al4.w*bf2f(v[3]);
  }
  float Dinv = (deg > 0) ? 1.f/(float)deg : 0.f;
  float v = acc*Dinv*0.25f + bias1[c];
  g_x1b[n*Hh + c] = f2bf((v >= 0.f) ? v : 0.2f*v);
}

// ---------------- K11: egs1->pb2 (0..255, 8 edges/blk, s4 loads) | mm2 MFMA + pa2 (256..511) ----------------
__global__ __launch_bounds__(256) void k_hc2a(const int* __restrict__ e){
  int blk = blockIdx.x, tid = threadIdx.x;
  if(blk < 256){
    __shared__ int srcs[8][32];
    __shared__ float w2as[Hh];
    if(tid < 128) w2as[tid] = g_w2a[tid];
    srcs[tid>>5][tid&31] = e[(blk*8 + (tid>>5)) + (tid&31)*Ee];
    __syncthreads();
    int eidx = tid >> 5, l32 = tid & 31, c0 = l32*4;
    float ac0 = 0.f, ac1 = 0.f, ac2 = 0.f, ac3 = 0.f;
    for(int k = 0; k < 32; k++){
      s4_t v = *(const s4_t*)(g_x1b + (size_t)srcs[eidx][k]*Hh + c0);
      ac0 += bf2f(v[0]); ac1 += bf2f(v[1]); ac2 += bf2f(v[2]); ac3 += bf2f(v[3]);
    }
    float p = ac0*w2as[c0] + ac1*w2as[c0+1] + ac2*w2as[c0+2] + ac3*w2as[c0+3];
    for(int o = 16; o > 0; o >>= 1) p += __shfl_xor(p, o);
    if(l32 == 0) g_pb2[blk*8 + eidx] = p;
  } else {
    int q = blk - 256;
    int bm = (q >> 1)*64, bn = (q & 1)*64;
    int epi = ((q & 1) == 0);
    __shared__ float w2xs[Hh];
    if(epi && tid < 128) w2xs[tid] = g_w2x[tid];
    __syncthreads();
    int wv = tid >> 6, lane = tid & 63;
    int nlo = lane & 15, quad = lane >> 4;
    int arow = bm + 16*wv + nlo;
    bf8_t a[4];
    #pragma unroll
    for(int kk = 0; kk < 4; kk++)
      a[kk] = *(const bf8_t*)(g_x1b + (size_t)arow*Hh + kk*32 + quad*8);
    bf8_t Wf[4][4];
    #pragma unroll
    for(int ct = 0; ct < 4; ct++){
      const short* wr0 = g_w2b + (size_t)(bn + 16*ct + nlo)*Hh;
      #pragma unroll
      for(int kk = 0; kk < 4; kk++)
        Wf[ct][kk] = *(const bf8_t*)(wr0 + kk*32 + quad*8);
    }
    f4_t acc[4];
    #pragma unroll
    for(int ct = 0; ct < 4; ct++){ f4_t z4; z4[0]=z4[1]=z4[2]=z4[3]=0.f; acc[ct]=z4; }
    #pragma unroll
    for(int ct = 0; ct < 4; ct++)
      #pragma unroll
      for(int kk = 0; kk < 4; kk++)
        acc[ct] = MFMA16(a[kk], Wf[ct][kk], acc[ct]);
    #pragma unroll
    for(int ct = 0; ct < 4; ct++)
      #pragma unroll
      for(int rr = 0; rr < 4; rr++)
        g_xw2b[(size_t)(bm + 16*wv + quad*4 + rr)*Hh + bn + 16*ct + nlo] = f2bf(acc[ct][rr]);
    if(epi){
      float s = 0.f;
      #pragma unroll
      for(int kk = 0; kk < 4; kk++)
        #pragma unroll
        for(int j = 0; j < 8; j++)
          s += bf2f(a[kk][j])*w2xs[kk*32 + quad*8 + j];
      s += __shfl_xor(s, 16);
      s += __shfl_xor(s, 32);
      if(quad == 0) g_pa2[arow] = s;
    }
  }
}

// ---------------- K13: eout2 (memoized alphas) ----------------
__global__ __launch_bounds__(128) void eout2_k(const int* __restrict__ e){
  __shared__ int srcs[32];
  __shared__ float al[32];
  int d = blockIdx.x, tid = threadIdx.x;
  if(tid < 32){
    srcs[tid] = e[d + tid*Ee];
    al[tid] = g_al2[d + tid*Ee];
  }
  __syncthreads();
  int c = tid;
  float acc = 0.f;
  for(int k = 0; k < 32; k++) acc += al[k]*bf2f(g_xw2b[srcs[k]*Hh + c]);
  g_eout2b[d*Hh + c] = f2bf(acc*(1.f/32.f));
}

// ---------------- K14: node_out2 + final projection (memoized alphas, shuffle reduce) ----------------
__global__ __launch_bounds__(128) void node_out2(const float* __restrict__ bias2,
                                                 const float* __restrict__ Wo, const float* __restrict__ bo,
                                                 float* __restrict__ out_x, float* __restrict__ out_o){
  int n = blockIdx.x, c = threadIdx.x;
  int start = g_rowptr[n], deg = g_rowptr[n+1] - start;
  float acc = 0.f;
  for(int j = 0; j < deg; j++){
    int i = g_eidx[start+j];
    int d = i & (Ee-1);
    float a = g_al2[i];
    acc += a*bf2f(g_eout2b[d*Hh + c]);
  }
  float Dinv = (deg > 0) ? 1.f/(float)deg : 0.f;
  float v = acc*Dinv + bias2[c];
  v = (v >= 0.f) ? v : 0.2f*v;
  out_x[n*Hh + c] = v;
  __shared__ float sh2[2];
  float p = v*Wo[c];
  for(int o = 32; o > 0; o >>= 1) p += __shfl_xor(p, o);
  if((c & 63) == 0) sh2[c >> 6] = p;
  __syncthreads();
  if(c == 0){
    float r = sh2[0] + sh2[1] + bo[0];
    r = (r >= 0.f) ? r : 0.01f*r;
    out_o[n] = r;
  }
}

extern "C" void kernel_launch(void* const* d_in, const int* in_sizes, int n_in,
                              void* d_out, int out_size, void* d_ws, size_t ws_size,
                              hipStream_t stream){
  const float* price = (const float*)d_in[0];
  const int*   e     = (const int*)  d_in[1];
  const float* bn1_g = (const float*)d_in[2];
  const float* bn1_b = (const float*)d_in[3];
  const float* W_ih  = (const float*)d_in[4];
  const float* W_hh  = (const float*)d_in[5];
  const float* b_ih  = (const float*)d_in[6];
  const float* b_hh  = (const float*)d_in[7];
  const float* Wq    = (const float*)d_in[8];
  const float* Wout  = (const float*)d_in[9];
  const float* ae    = (const float*)d_in[10];
  const float* ab    = (const float*)d_in[11];
  const float* bn2_g = (const float*)d_in[12];
  const float* bn2_b = (const float*)d_in[13];
  const float* W1    = (const float*)d_in[14];
  const float* att1  = (const float*)d_in[15];
  const float* bias1 = (const float*)d_in[16];
  const float* W2    = (const float*)d_in[17];
  const float* att2  = (const float*)d_in[18];
  const float* bias2 = (const float*)d_in[19];
  const float* Wo    = (const float*)d_in[20];
  const float* bo    = (const float*)d_in[21];

  float* out_nf = (float*)d_out;
  float* out_x  = out_nf + Nn*Hh;
  float* out_o  = out_nf + 2*Nn*Hh;

  k_pre<<<521, 256, 0, stream>>>(price, W1, att1, W2, att2, Wout);
  k_fin_count<<<320, 256, 0, stream>>>(e);
  k_apply_scan<<<257, 256, 0, stream>>>(price, bn1_g, bn1_b);
  k_gru_fill<<<640, 512, 0, stream>>>(W_ih, W_hh, b_ih, b_hh, Wq, e);
  attn_mid<<<Nn, 128, 0, stream>>>(ae, ab);
  k_gemm_out<<<256, 128, 0, stream>>>(out_nf);
  k_hc1a<<<1280, 256, 0, stream>>>(e, bn2_g, bn2_b);
  seg_stats1<<<Nn, 64, 0, stream>>>();
  eout1_k<<<Ee, 128, 0, stream>>>(e);
  node_out1<<<Nn, 128, 0, stream>>>(bias1);
  k_hc2a<<<512, 256, 0, stream>>>(e);
  seg_stats2<<<Nn, 64, 0, stream>>>();
  eout2_k<<<Ee, 128, 0, stream>>>(e);
  node_out2<<<Nn, 128, 0, stream>>>(bias2, Wo, bo, out_x, out_o);

  (void)in_sizes; (void)n_in; (void)out_size; (void)d_ws; (void)ws_size;
}